// Round 9
// baseline (5138.928 us; speedup 1.0000x reference)
//
#include <hip/hip_runtime.h>
#include <math.h>

#define T_ 200
#define SMEM_FLOATS ((128 + 16) * 256)
#define SMEM_BYTES (SMEM_FLOATS * 4)   // 147,456 <= 163,840 (160 KiB)

__device__ __forceinline__ float fsig(float x) {
  return 1.f / (1.f + __expf(-x));
}
__device__ __forceinline__ float ftanh(float x) {
  return 1.f - 2.f / (__expf(2.f * x) + 1.f);   // exact at +-inf, no NaN
}
// XOR swizzle: spreads k bits 5-7 into bank bits 2-4; quad-aligned preserving.
__device__ __forceinline__ int swz(int k) {
  return k ^ (((k >> 5) & 7) << 2);
}

// ---------------- xg GEMM v3: both dirs in one launch (grid.z), 128x128 tile,
// 8x8 micro, fused embedding gather, masked-tile early exit, B-read swizzle
// (was 4-way bank conflict on every B b128 read).
__global__ __launch_bounds__(256) void xg_gemm(
    const int* __restrict__ bin, const int* __restrict__ bfe,
    const int* __restrict__ blen,
    const float* __restrict__ ctab, const float* __restrict__ ftab,
    const float* __restrict__ wihf, const float* __restrict__ biasf,
    const float* __restrict__ wihb, const float* __restrict__ biasb,
    float* __restrict__ xgf, float* __restrict__ xgb, int t0f, int t0b) {
  const int dir = blockIdx.z;
  const int t0 = dir ? t0b : t0f;
  const int sgn = dir ? -1 : 1;
  const float* wih = dir ? wihb : wihf;
  const float* bias = dir ? biasb : biasf;
  float* xgslot = dir ? xgb : xgf;

  const int m0 = blockIdx.x * 128;
  const int rloc = m0 >> 8;
  const int t_blk = t0 + sgn * rloc;
  if (t_blk >= blen[m0 & 255]) return;   // fully masked tile (sorted lengths)

  __shared__ float As[32][140];   // [k][m swizzled]
  __shared__ float Bs[32][140];   // [k][n swizzled]
  const int tid = threadIdx.x;
  const int n0 = blockIdx.y * 128;
  const int mm = tid & 15;
  const int nn = tid >> 4;

  const int ra = tid & 127;            // staging row (A: m, B: n)
  const int ka = (tid >> 7) << 4;      // k-offset 0 or 16

  const int bcol = (m0 + ra) & 255;
  const float* cr = ctab + ((size_t)bin[bcol * T_ + t_blk] << 8);
  const float* fr = ftab + ((size_t)bfe[bcol * T_ + t_blk] << 8);
  const float* br = wih + (size_t)(n0 + ra) * 256;
  const int cwa = ra + ((ra >> 5) << 2);   // swizzled col for row index ra

  float acc[8][8];
  #pragma unroll
  for (int i = 0; i < 8; ++i)
    #pragma unroll
    for (int j = 0; j < 8; ++j) acc[i][j] = 0.f;

  const int am0 = mm * 8 + ((mm >> 2) << 2);   // swizzled base col (A reads)
  const int bn0 = nn * 8 + ((nn >> 2) << 2);   // swizzled base col (B reads)
  const int ln0 = nn * 8;                      // logical n offset (bias/out)

  for (int ks = 0; ks < 256; ks += 32) {
    float4 c4[4], f4v[4], b4[4];
    #pragma unroll
    for (int w = 0; w < 4; ++w) {
      c4[w]  = *(const float4*)(cr + ks + ka + w * 4);
      f4v[w] = *(const float4*)(fr + ks + ka + w * 4);
      b4[w]  = *(const float4*)(br + ks + ka + w * 4);
    }
    __syncthreads();   // previous iteration's consumers done
    #pragma unroll
    for (int w = 0; w < 4; ++w) {
      int kk = ka + w * 4;
      As[kk + 0][cwa] = c4[w].x * f4v[w].x;
      As[kk + 1][cwa] = c4[w].y * f4v[w].y;
      As[kk + 2][cwa] = c4[w].z * f4v[w].z;
      As[kk + 3][cwa] = c4[w].w * f4v[w].w;
      Bs[kk + 0][cwa] = b4[w].x;
      Bs[kk + 1][cwa] = b4[w].y;
      Bs[kk + 2][cwa] = b4[w].z;
      Bs[kk + 3][cwa] = b4[w].w;
    }
    __syncthreads();
    #pragma unroll 4
    for (int k = 0; k < 32; ++k) {
      float4 a0 = *(const float4*)&As[k][am0];
      float4 a1 = *(const float4*)&As[k][am0 + 4];
      float4 b0 = *(const float4*)&Bs[k][bn0];
      float4 b1 = *(const float4*)&Bs[k][bn0 + 4];
      float am[8] = {a0.x, a0.y, a0.z, a0.w, a1.x, a1.y, a1.z, a1.w};
      float bn[8] = {b0.x, b0.y, b0.z, b0.w, b1.x, b1.y, b1.z, b1.w};
      #pragma unroll
      for (int i = 0; i < 8; ++i)
        #pragma unroll
        for (int j = 0; j < 8; ++j)
          acc[i][j] += am[i] * bn[j];
    }
  }

  float4 bv0 = *(const float4*)(bias + n0 + ln0);
  float4 bv1 = *(const float4*)(bias + n0 + ln0 + 4);
  #pragma unroll
  for (int i = 0; i < 8; ++i) {
    int row = m0 + mm * 8 + i;
    float4 o0, o1;
    o0.x = acc[i][0] + bv0.x; o0.y = acc[i][1] + bv0.y;
    o0.z = acc[i][2] + bv0.z; o0.w = acc[i][3] + bv0.w;
    o1.x = acc[i][4] + bv1.x; o1.y = acc[i][5] + bv1.y;
    o1.z = acc[i][6] + bv1.z; o1.w = acc[i][7] + bv1.w;
    *(float4*)(xgslot + (size_t)row * 1024 + n0 + ln0) = o0;
    *(float4*)(xgslot + (size_t)row * 1024 + n0 + ln0 + 4) = o1;
  }
}

// ---------------- persistent LSTM chunk v6: ks16 tile (min LDS traffic:
// 512 b128 instrs/step/block vs 768 in r8) + XOR swizzle (stride 256) +
// sc1-only dwordx4 staging (r8-proven) + fetch_add barrier (r8-proven).
// grid (16 bc, 8 js, 2 dir) = 256 blocks x 512 thr, 1 block/CU.
// Thread (ks=tid&15, bg=(tid>>4)&1, rg=tid>>5): 8 rows x 8 batches x 16 k.
// W rows permuted: prow = rgs*8 + g*2 + u <-> Whh[g*256 + js*32 + rgs*2 + u].
// Butterfly (r7-verified): xor1/2/4 route 8 batches (batch = ks&7),
// xor8 pure k-reduce; u = ks>>3 picks j within the thread's row pair.
__global__ __launch_bounds__(512, 1) void lstm_chunk(
    const float* __restrict__ xgf, const float* __restrict__ xgb,
    const float* __restrict__ whf, const float* __restrict__ whb,
    const int* __restrict__ blen,
    float* __restrict__ hst, float* __restrict__ cst,
    float* __restrict__ hout, unsigned* __restrict__ bar,
    int s0, int nsteps) {
  extern __shared__ float smem[];
  float* wlds = smem;                 // [128][256] swizzled
  float* hlds = smem + 128 * 256;     // [16][256] swizzled

  const int bc = blockIdx.x, js = blockIdx.y, dir = blockIdx.z;
  const int tid = threadIdx.x;
  const int ks = tid & 15;
  const int bg = (tid >> 4) & 1;
  const int rg = tid >> 5;            // 0..15
  const int grp = dir * 16 + bc;
  const float* wh = dir ? whb : whf;
  const float* xgp = dir ? xgb : xgf;

  // ---- stage W once per chunk (permuted rows, XOR-swizzled cols)
  #pragma unroll
  for (int i = 0; i < 16; ++i) {
    int f = tid + i * 512;            // float4 id 0..8191
    int prow = f >> 6;
    int k = (f & 63) << 2;
    int g = (prow >> 1) & 3, u = prow & 1, rgs = prow >> 3;
    int jg = js * 32 + rgs * 2 + u;
    float4 v = *(const float4*)(wh + ((size_t)(g * 256 + jg)) * 256 + k);
    *(float4*)&wlds[prow * 256 + swz(k)] = v;
  }

  const int bl_th = bg * 8 + (ks & 7);      // local batch 0..15
  const int b_th = bc * 16 + bl_th;
  const int u_th = ks >> 3;
  const int jth = js * 32 + rg * 2 + u_th;
  const int cjth = swz(jth);
  const int len_th = blen[b_th];
  float c0 = cst[((size_t)dir * 256 + b_th) * 256 + jth];

  // per-thread GEMM columns (loop-invariant): k = ks*16 + kq*4, swizzled
  int colv[4];
  #pragma unroll
  for (int kq = 0; kq < 4; ++kq) colv[kq] = swz(ks * 16 + kq * 4);

  __syncthreads();   // W staged

  for (int r = 0; r < nsteps; ++r) {
    const int s = s0 + r;
    const int tt = dir ? (199 - s) : s;
    const int rslot = s & 1, wslot = 1 - rslot;

    // ---- xq loads first (latency hidden under staging + GEMM)
    float xq[4];
    #pragma unroll
    for (int g = 0; g < 4; ++g)
      xq[g] = xgp[((size_t)r * 256 + b_th) * 1024 + g * 256 + jth];

    // ---- stage h[16 b][256 k]: 2 agent-scope (sc1) dwordx4 per thread
    const float* hsrc = hst + (((size_t)(rslot * 2 + dir)) * 256 + bc * 16) * 256;
    {
      const int f0 = tid, f1 = tid + 512;        // float4 ids
      const int b0i = f0 >> 6, k0 = (f0 & 63) << 2;
      const int b1i = f1 >> 6, k1 = (f1 & 63) << 2;
      const float* p0 = hsrc + (b0i << 8) + k0;
      const float* p1 = hsrc + (b1i << 8) + k1;
      float4 v0, v1;
      asm volatile(
          "global_load_dwordx4 %0, %2, off sc1\n\t"
          "global_load_dwordx4 %1, %3, off sc1\n\t"
          "s_waitcnt vmcnt(0)"
          : "=&v"(v0), "=&v"(v1)
          : "v"(p0), "v"(p1)
          : "memory");
      *(float4*)&hlds[b0i * 256 + swz(k0)] = v0;
      *(float4*)&hlds[b1i * 256 + swz(k1)] = v1;
    }
    __syncthreads();

    // ---- GEMM: acc[i][bb] over this thread's 16-k slice
    float acc[8][8];
    #pragma unroll
    for (int i = 0; i < 8; ++i)
      #pragma unroll
      for (int bb = 0; bb < 8; ++bb) acc[i][bb] = 0.f;

    #pragma unroll
    for (int kq = 0; kq < 4; ++kq) {
      const int col = colv[kq];
      float4 h4[8];
      #pragma unroll
      for (int bb = 0; bb < 8; ++bb)
        h4[bb] = *(const float4*)&hlds[(bg * 8 + bb) * 256 + col];
      #pragma unroll
      for (int i = 0; i < 8; ++i) {
        float4 w4 = *(const float4*)&wlds[(rg * 8 + i) * 256 + col];
        #pragma unroll
        for (int bb = 0; bb < 8; ++bb)
          acc[i][bb] += w4.x * h4[bb].x + w4.y * h4[bb].y +
                        w4.z * h4[bb].z + w4.w * h4[bb].w;
      }
    }

    // ---- pair-halving butterfly over ks (r7-verified): 64 -> 32 -> 16 -> 8
    const int bit0 = ks & 1, bit1 = (ks >> 1) & 1, bit2 = (ks >> 2) & 1;
    float rd1[8][4];
    #pragma unroll
    for (int i = 0; i < 8; ++i)
      #pragma unroll
      for (int m = 0; m < 4; ++m) {
        float keep = bit0 ? acc[i][2 * m + 1] : acc[i][2 * m];
        float send = bit0 ? acc[i][2 * m] : acc[i][2 * m + 1];
        rd1[i][m] = keep + __shfl_xor(send, 1);
      }
    float rd2[8][2];
    #pragma unroll
    for (int i = 0; i < 8; ++i)
      #pragma unroll
      for (int m = 0; m < 2; ++m) {
        float keep = bit1 ? rd1[i][2 * m + 1] : rd1[i][2 * m];
        float send = bit1 ? rd1[i][2 * m] : rd1[i][2 * m + 1];
        rd2[i][m] = keep + __shfl_xor(send, 2);
      }
    float fin[8];
    #pragma unroll
    for (int i = 0; i < 8; ++i) {
      float keep = bit2 ? rd2[i][1] : rd2[i][0];
      float send = bit2 ? rd2[i][0] : rd2[i][1];
      float z = keep + __shfl_xor(send, 4);
      fin[i] = z + __shfl_xor(z, 8);
    }

    // ---- cell update (1 cell per thread: batch b_th, hidden jth)
    float gi = fsig(fin[0 + u_th] + xq[0]);
    float gf = fsig(fin[2 + u_th] + xq[1]);
    float gg = ftanh(fin[4 + u_th] + xq[2]);
    float go = fsig(fin[6 + u_th] + xq[3]);
    float cn = gf * c0 + gi * gg;
    float hn = go * ftanh(cn);
    const bool mk = tt < len_th;
    if (mk) c0 = cn;
    float hold = hlds[bl_th * 256 + cjth];
    float hsv = mk ? hn : hold;
    __hip_atomic_store(
        hst + (((size_t)(wslot * 2 + dir)) * 256 + b_th) * 256 + jth,
        hsv, __ATOMIC_RELAXED, __HIP_MEMORY_SCOPE_AGENT);

    // ---- drain h stores, signal, hout store overlaps the poll
    asm volatile("s_waitcnt vmcnt(0)" ::: "memory");
    __syncthreads();
    if (tid == 0)
      __hip_atomic_fetch_add(&bar[grp * 32], 1u, __ATOMIC_RELAXED,
                             __HIP_MEMORY_SCOPE_AGENT);
    hout[(((size_t)dir * 200 + tt) * 256 + b_th) * 256 + jth] = mk ? hn : 0.f;
    if (tid == 0) {
      const unsigned tgt = 8u * (unsigned)(s + 1);
      while (__hip_atomic_load(&bar[grp * 32], __ATOMIC_RELAXED,
                               __HIP_MEMORY_SCOPE_AGENT) < tgt) {}
    }
    __syncthreads();
  }

  cst[((size_t)dir * 256 + b_th) * 256 + jth] = c0;
}

// ---------------- feats[b][t][k] = [hf|hb] . W_tag[k] + b_tag[k]  (r2, proven)
__global__ __launch_bounds__(256) void feats_kernel(
    const float* __restrict__ h_out, const float* __restrict__ wtag,
    const float* __restrict__ btag, float* __restrict__ feats) {
  __shared__ float hcat[32][512];
  const int t = blockIdx.x, bc = blockIdx.y;
  const int tid = threadIdx.x;
  const float* hf = h_out + (((size_t)0 * 200 + t) * 256 + bc * 32) * 256;
  const float* hb = h_out + (((size_t)1 * 200 + t) * 256 + bc * 32) * 256;
  for (int i = tid; i < 2048; i += 256) {
    int row = i >> 6, c4 = (i & 63) << 2;
    *(float4*)&hcat[row][c4] = *(const float4*)(hf + (size_t)row * 256 + c4);
    *(float4*)&hcat[row][256 + c4] = *(const float4*)(hb + (size_t)row * 256 + c4);
  }
  __syncthreads();
  const int kk = tid & 63;
  const int bg = tid >> 6;
  if (kk < 52) {
    float acc[8];
    #pragma unroll
    for (int i = 0; i < 8; ++i) acc[i] = 0.f;
    const float* wr = wtag + (size_t)kk * 512;
    for (int jq = 0; jq < 128; ++jq) {
      float4 wv = *(const float4*)(wr + jq * 4);
      #pragma unroll
      for (int bi = 0; bi < 8; ++bi) {
        float4 hv = *(const float4*)&hcat[bg * 8 + bi][jq * 4];
        acc[bi] += wv.x * hv.x + wv.y * hv.y + wv.z * hv.z + wv.w * hv.w;
      }
    }
    float bv = btag[kk];
    #pragma unroll
    for (int bi = 0; bi < 8; ++bi)
      feats[(size_t)(bc * 32 + bg * 8 + bi) * 10400 + t * 52 + kk] = acc[bi] + bv;
  }
}

// ---------------- Viterbi v3 (r7/r8, proven absmax 0): one WAVE per batch row.
__global__ __launch_bounds__(64) void viterbi_kernel(
    const float* __restrict__ feats, const float* __restrict__ trans,
    const int* __restrict__ blen, float* __restrict__ out) {
  __shared__ float flds[10400];
  __shared__ float pl[56];
  __shared__ unsigned char bp[199 * 52];

  const int b = blockIdx.x;
  const int lane = threadIdx.x;
  const int kk = (lane < 52) ? lane : 0;
  const float* fb = feats + (size_t)b * 10400;
  const int len = blen[b];

  for (int i = lane; i < 2600; i += 64)
    *(float4*)&flds[i * 4] = *(const float4*)(fb + i * 4);

  float trc[52];
  #pragma unroll
  for (int j = 0; j < 52; ++j) trc[j] = trans[j * 52 + kk];
  __syncthreads();

  float part = trans[50 * 52 + kk] + flds[kk];   // START row = 50
  if (lane < 52) pl[lane] = part;

  for (int t = 1; t < 200; ++t) {
    const float ftk = flds[t * 52 + kk];
    float pa[52];
    #pragma unroll
    for (int q = 0; q < 13; ++q) {
      float4 v = *(const float4*)&pl[q * 4];
      pa[q * 4 + 0] = v.x; pa[q * 4 + 1] = v.y;
      pa[q * 4 + 2] = v.z; pa[q * 4 + 3] = v.w;
    }
    float mv0 = -1e30f, mv1 = -1e30f, mv2 = -1e30f, mv3 = -1e30f;
    int mj0 = 0, mj1 = 13, mj2 = 26, mj3 = 39;
    #pragma unroll
    for (int q = 0; q < 13; ++q) {
      float c0v = (pa[q] + trc[q]) + ftk;
      if (c0v > mv0) { mv0 = c0v; mj0 = q; }
      float c1v = (pa[13 + q] + trc[13 + q]) + ftk;
      if (c1v > mv1) { mv1 = c1v; mj1 = 13 + q; }
      float c2v = (pa[26 + q] + trc[26 + q]) + ftk;
      if (c2v > mv2) { mv2 = c2v; mj2 = 26 + q; }
      float c3v = (pa[39 + q] + trc[39 + q]) + ftk;
      if (c3v > mv3) { mv3 = c3v; mj3 = 39 + q; }
    }
    float mv = mv0; int mj = mj0;
    if (mv1 > mv) { mv = mv1; mj = mj1; }
    if (mv2 > mv) { mv = mv2; mj = mj2; }
    if (mv3 > mv) { mv = mv3; mj = mj3; }
    const bool m = t < len;
    if (lane < 52) {
      bp[(t - 1) * 52 + lane] = (unsigned char)(m ? mj : lane);
      if (m) { part = mv; pl[lane] = mv; }
    }
  }

  float fin = (lane < 52) ? (part + trans[lane * 52 + 51]) : -1e30f;
  int bi = lane;
  #pragma unroll
  for (int off = 32; off; off >>= 1) {
    float ov = __shfl_down(fin, off);
    int oi = __shfl_down(bi, off);
    if (ov > fin || (ov == fin && oi < bi)) { fin = ov; bi = oi; }
  }
  if (lane == 0) {
    out[b] = fin;
    int tag = bi;
    float* dec = out + 256 + (size_t)b * 200;
    dec[199] = (199 < len) ? (float)tag : 0.f;
    for (int i = 198; i >= 0; --i) {
      tag = bp[i * 52 + tag];
      dec[i] = (i < len) ? (float)tag : 0.f;
    }
  }
}

extern "C" void kernel_launch(void* const* d_in, const int* in_sizes, int n_in,
                              void* d_out, int out_size, void* d_ws, size_t ws_size,
                              hipStream_t stream) {
  const int*   bin  = (const int*)d_in[0];
  const int*   bfe  = (const int*)d_in[1];
  const int*   blen = (const int*)d_in[2];
  const float* ctab = (const float*)d_in[5];
  const float* ftab = (const float*)d_in[6];
  const float* wihf = (const float*)d_in[7];
  const float* whhf = (const float*)d_in[8];
  const float* bf   = (const float*)d_in[9];
  const float* wihb = (const float*)d_in[10];
  const float* whhb = (const float*)d_in[11];
  const float* bb   = (const float*)d_in[12];
  const float* wtag = (const float*)d_in[13];
  const float* btag = (const float*)d_in[14];
  const float* trn  = (const float*)d_in[15];

  (void)hipFuncSetAttribute(reinterpret_cast<const void*>(lstm_chunk),
                            hipFuncAttributeMaxDynamicSharedMemorySize,
                            SMEM_BYTES);

  const size_t FIXED_F = 29271040;
  size_t ws_f = ws_size / sizeof(float);
  int C = 1;
  const int cands[10] = {50, 40, 25, 20, 10, 8, 5, 4, 2, 1};
  for (int u = 0; u < 10; ++u) {
    if (FIXED_F + (size_t)2 * cands[u] * 262144 <= ws_f) { C = cands[u]; break; }
  }

  float* ws  = (float*)d_ws;
  float* xgf = ws;
  float* xgb = xgf + (size_t)C * 262144;
  float* hst = xgb + (size_t)C * 262144;    // 2 slots x 2 dir x 256 x 256
  float* cst = hst + 262144;
  float* hout = cst + 131072;               // 2 dir x 200 x 256 x 256
  float* fts  = hout + 26214400;
  unsigned* bar = (unsigned*)(fts + 2662400); // 32 groups x stride 32
  float* out  = (float*)d_out;

  hipMemsetAsync(hst, 0, (size_t)(262144 + 131072) * sizeof(float), stream);
  hipMemsetAsync(bar, 0, 1024 * sizeof(unsigned), stream);

  const int nchunks = 200 / C;
  for (int c = 0; c < nchunks; ++c) {
    xg_gemm<<<dim3(2 * C, 8, 2), 256, 0, stream>>>(
        bin, bfe, blen, ctab, ftab, wihf, bf, wihb, bb,
        xgf, xgb, c * C, 199 - c * C);
    lstm_chunk<<<dim3(16, 8, 2), 512, SMEM_BYTES, stream>>>(
        xgf, xgb, whhf, whhb, blen, hst, cst, hout, bar, c * C, C);
  }
  feats_kernel<<<dim3(200, 8), 256, 0, stream>>>(hout, wtag, btag, fts);
  viterbi_kernel<<<256, 64, 0, stream>>>(fts, trn, blen, out);
}